// Round 7
// baseline (475.793 us; speedup 1.0000x reference)
//
#include <hip/hip_runtime.h>

#define PAST 12
#define FUTURE 12
#define NB 64
#define NL 256
#define ND 512
#define NW 244  // NL - PAST

typedef unsigned short ushort_t;
typedef __attribute__((ext_vector_type(8))) short short8;
typedef __attribute__((ext_vector_type(4))) float floatx4;

__device__ inline unsigned int f2bf(float x) {
    unsigned int u = __float_as_uint(x);
    return (u + 0x7fffu + ((u >> 16) & 1u)) >> 16;  // RNE
}

// ---------------- Stage 0a: inp fp32 -> bf16 (8 elems/thread) ----------------
// XCD-chunked swizzle matched to the GEMM consumer: XCD k converts A-rows
// [2048k, 2048(k+1)) so the bf16 A panel is resident in the consumer's L2.
__global__ __launch_bounds__(256) void convert_inp(
    const float* __restrict__ in, ushort_t* __restrict__ out)
{
    const int swz = (blockIdx.x & 7) * 512 + (blockIdx.x >> 3);  // 4096 blocks, %8==0
    const int i = (swz * 256 + threadIdx.x) * 8;                 // 8,388,608 elems, /8 exact
    const float4 v0 = *(const float4*)(in + i);
    const float4 v1 = *(const float4*)(in + i + 4);
    uint4 o;
    o.x = f2bf(v0.x) | (f2bf(v0.y) << 16);
    o.y = f2bf(v0.z) | (f2bf(v0.w) << 16);
    o.z = f2bf(v1.x) | (f2bf(v1.y) << 16);
    o.w = f2bf(v1.z) | (f2bf(v1.w) << 16);
    *(uint4*)(out + i) = o;
}

// ---------------- Stage 0b: W_s fp32 -> bf16, and S[e] = sum_d W_s[e][d] ----------------
__global__ __launch_bounds__(256) void prep_ws(
    const float* __restrict__ Ws, ushort_t* __restrict__ Wsb, float* __restrict__ S)
{
    const int row = blockIdx.x;       // 0..511
    const int t = threadIdx.x;        // 0..255
    const float2 v = *(const float2*)(Ws + (size_t)row * ND + t * 2);
    *(unsigned int*)(Wsb + (size_t)row * ND + t * 2) = f2bf(v.x) | (f2bf(v.y) << 16);
    float s = v.x + v.y;
#pragma unroll
    for (int o = 32; o > 0; o >>= 1) s += __shfl_down(s, o);
    __shared__ float red[4];
    if ((t & 63) == 0) red[t >> 6] = s;
    __syncthreads();
    if (t == 0) S[row] = red[0] + red[1] + red[2] + red[3];
}

// ---------------- Stage 1: y = inp @ W_s^T  (LDS-free, barrier-free MFMA GEMM) ----------------
// B is 0.5 MB (L2-resident); A bf16 is 16.8 MB, L2-local per XCD under the chunked swizzle
// with each A line reused 8x by the n-blocks of its m-panel. Fragments load straight from
// global (short8, 16 B/lane); no LDS, no __syncthreads, no vmcnt(0) drains. Latency hidden
// by 8 blocks/CU (grid 2048, no LDS/VGPR occupancy cap).
#define BM 64
#define BN 64

__global__ __launch_bounds__(256) void gemm_spatial(
    const ushort_t* __restrict__ A,    // bf16 [16384, 512]
    const ushort_t* __restrict__ Bm,   // bf16 [512, 512]
    ushort_t* __restrict__ Y)          // bf16 [16384, 512]
{
    const int tid  = threadIdx.x;
    const int wave = tid >> 6;
    const int lane = tid & 63;

    // bijective chunked XCD swizzle (2048 blocks): XCD k gets idx [256k, 256k+256)
    const int bid = blockIdx.x;
    const int idx = (bid & 7) * 256 + (bid >> 3);
    const int n0 = (idx & 7) * BN;     // n fastest: 8 n-blocks of one m-panel adjacent in-XCD
    const int m0 = (idx >> 3) * BM;
    const int wm = (wave >> 1) * 32;   // waves 2x2, each owns 32x32
    const int wn = (wave & 1) * 32;

    // fragment base addresses: row = (lane&15), k-chunk = (lane>>4)*8
    const ushort_t* a0 = A  + (size_t)(m0 + wm + (lane & 15)) * ND + (lane >> 4) * 8;
    const ushort_t* b0 = Bm + (size_t)(n0 + wn + (lane & 15)) * ND + (lane >> 4) * 8;

    floatx4 acc[2][2] = {};

#pragma unroll 4
    for (int k0 = 0; k0 < ND; k0 += 32) {
        short8 af[2], bq[2];
        af[0] = *(const short8*)(a0 + k0);
        af[1] = *(const short8*)(a0 + (size_t)16 * ND + k0);
        bq[0] = *(const short8*)(b0 + k0);
        bq[1] = *(const short8*)(b0 + (size_t)16 * ND + k0);
#pragma unroll
        for (int i = 0; i < 2; ++i)
#pragma unroll
            for (int j = 0; j < 2; ++j)
                acc[i][j] = __builtin_amdgcn_mfma_f32_16x16x32_bf16(af[i], bq[j], acc[i][j], 0, 0, 0);
    }

#pragma unroll
    for (int i = 0; i < 2; ++i) {
        const int m_base = m0 + wm + i * 16 + (lane >> 4) * 4;
#pragma unroll
        for (int j = 0; j < 2; ++j) {
            const int n = n0 + wn + j * 16 + (lane & 15);
#pragma unroll
            for (int r = 0; r < 4; ++r) {
                Y[(size_t)(m_base + r) * ND + n] = (ushort_t)f2bf(acc[i][j][r]);
            }
        }
    }
}

// ---------------- Stage 2: temporal mix + biases (fp32 out, nontemporal float4 stores) ----------------
// out[b,w,f,e] = sum_p W_t[f,p]*y[b,w+p,e] + b_t[f]*S[e] + b_s[e]
// Chunked XCD swizzle: XCD k <- batches [8k, 8k+8), matching the GEMM's Y placement.
#define WTILE 8
#define TGRID (((NW + WTILE - 1) / WTILE) * NB)   // 31 * 64 = 1984, % 8 == 0

__global__ __launch_bounds__(256) void temporal_kernel(
    const ushort_t* __restrict__ Y,    // [64*256, 512] bf16
    const float*    __restrict__ Wt,   // [12,12] fp32 (wave-uniform -> s_load)
    const float*    __restrict__ bt,   // [12] fp32
    const float*    __restrict__ bs,   // [512] fp32
    const float*    __restrict__ S,    // [512] fp32
    float*          __restrict__ Out)  // [64,244,12,512] fp32
{
    const int tid = threadIdx.x;
    const int bid = blockIdx.x;
    const int idx = (bid & 7) * (TGRID / 8) + (bid >> 3);   // bijective (1984 % 8 == 0)
    const int b   = idx / 31;          // XCD k gets b in [8k, 8k+8)
    const int wx  = idx % 31;
    const int w0 = wx * WTILE + (tid >> 7) * 4;  // half-block w-base
    const int eq = (tid & 127) * 4;

    const float4 Sv  = *(const float4*)(S + eq);
    const float4 bsv = *(const float4*)(bs + eq);

    // 15-row sliding window, 4 e's per thread, registers only (all indices constant)
    float win[PAST + 3][4];
    const ushort_t* ybase = Y + ((size_t)(b * NL + w0)) * ND + eq;
#pragma unroll
    for (int i = 0; i < PAST + 3; ++i) {
        if (w0 + i < NL) {
            const uint2 v = *(const uint2*)(ybase + (size_t)i * ND);
            win[i][0] = __uint_as_float(v.x << 16);
            win[i][1] = __uint_as_float(v.x & 0xffff0000u);
            win[i][2] = __uint_as_float(v.y << 16);
            win[i][3] = __uint_as_float(v.y & 0xffff0000u);
        } else {
            win[i][0] = win[i][1] = win[i][2] = win[i][3] = 0.f;
        }
    }

#pragma unroll
    for (int w = 0; w < 4; ++w) {
        if (w0 + w < NW) {
            float* orow = Out + ((size_t)(b * NW + (w0 + w)) * FUTURE) * ND + eq;
#pragma unroll
            for (int f = 0; f < FUTURE; ++f) {
                const float btf = bt[f];                    // uniform -> SGPR
                float a0 = fmaf(btf, Sv.x, bsv.x);
                float a1 = fmaf(btf, Sv.y, bsv.y);
                float a2 = fmaf(btf, Sv.z, bsv.z);
                float a3 = fmaf(btf, Sv.w, bsv.w);
#pragma unroll
                for (int p = 0; p < PAST; ++p) {
                    const float c = Wt[f * PAST + p];       // uniform -> SGPR
                    a0 = fmaf(c, win[w + p][0], a0);
                    a1 = fmaf(c, win[w + p][1], a1);
                    a2 = fmaf(c, win[w + p][2], a2);
                    a3 = fmaf(c, win[w + p][3], a3);
                }
                // streaming output, never re-read: bypass L2/L3 (ext_vector type required)
                floatx4 ov;
                ov.x = a0; ov.y = a1; ov.z = a2; ov.w = a3;
                __builtin_nontemporal_store(ov, (floatx4*)(orow + (size_t)f * ND));
            }
        }
    }
}

// ---------------- launch ----------------
extern "C" void kernel_launch(void* const* d_in, const int* in_sizes, int n_in,
                              void* d_out, int out_size, void* d_ws, size_t ws_size,
                              hipStream_t stream) {
    const float* inp = (const float*)d_in[0];  // [64,256,512] fp32
    const float* Wt  = (const float*)d_in[1];  // [12,12]
    const float* bt  = (const float*)d_in[2];  // [12]
    const float* Ws  = (const float*)d_in[3];  // [512,512]
    const float* bs  = (const float*)d_in[4];  // [512]
    float* out = (float*)d_out;

    const size_t n_inp = (size_t)NB * NL * ND;            // 8,388,608
    ushort_t* Y     = (ushort_t*)d_ws;                               // 16.8 MB
    ushort_t* inp_b = (ushort_t*)((char*)d_ws + n_inp * 2);          // +16.8 MB
    ushort_t* Ws_b  = (ushort_t*)((char*)d_ws + n_inp * 4);          // +0.5 MB
    float*    S     = (float*)((char*)d_ws + n_inp * 4 + (size_t)ND * ND * 2);

    prep_ws<<<dim3(ND), dim3(256), 0, stream>>>(Ws, Ws_b, S);
    convert_inp<<<dim3(n_inp / 8 / 256), dim3(256), 0, stream>>>(inp, inp_b);
    gemm_spatial<<<dim3((NB * NL / BM) * (ND / BN)), dim3(256), 0, stream>>>(inp_b, Ws_b, Y);
    temporal_kernel<<<dim3(TGRID), dim3(256), 0, stream>>>(Y, Wt, bt, bs, S, out);
}

// Round 9
// 431.678 us; speedup vs baseline: 1.1022x; 1.1022x over previous
//
#include <hip/hip_runtime.h>

#define PAST 12
#define FUTURE 12
#define NB 64
#define NL 256
#define ND 512
#define NW 244  // NL - PAST

typedef unsigned short ushort_t;
typedef __attribute__((ext_vector_type(8))) short short8;
typedef __attribute__((ext_vector_type(4))) float floatx4;

__device__ inline unsigned int f2bf(float x) {
    unsigned int u = __float_as_uint(x);
    return (u + 0x7fffu + ((u >> 16) & 1u)) >> 16;  // RNE
}

// ---------------- Stage 0a: inp fp32 -> bf16 (8 elems/thread) ----------------
// XCD-chunked swizzle matched to the GEMM consumer: XCD k converts A-rows
// [2048k, 2048(k+1)) = m-panels [16k, 16k+16), exactly the GEMM XCD k's panels.
__global__ __launch_bounds__(256) void convert_inp(
    const float* __restrict__ in, ushort_t* __restrict__ out)
{
    const int swz = (blockIdx.x & 7) * 512 + (blockIdx.x >> 3);  // 4096 blocks, %8==0
    const int i = (swz * 256 + threadIdx.x) * 8;                 // 8,388,608 elems, /8 exact
    const float4 v0 = *(const float4*)(in + i);
    const float4 v1 = *(const float4*)(in + i + 4);
    uint4 o;
    o.x = f2bf(v0.x) | (f2bf(v0.y) << 16);
    o.y = f2bf(v0.z) | (f2bf(v0.w) << 16);
    o.z = f2bf(v1.x) | (f2bf(v1.y) << 16);
    o.w = f2bf(v1.z) | (f2bf(v1.w) << 16);
    *(uint4*)(out + i) = o;
}

// ---------------- Stage 0b: W_s fp32 -> bf16, and S[e] = sum_d W_s[e][d] ----------------
__global__ __launch_bounds__(256) void prep_ws(
    const float* __restrict__ Ws, ushort_t* __restrict__ Wsb, float* __restrict__ S)
{
    const int row = blockIdx.x;       // 0..511
    const int t = threadIdx.x;        // 0..255
    const float2 v = *(const float2*)(Ws + (size_t)row * ND + t * 2);
    *(unsigned int*)(Wsb + (size_t)row * ND + t * 2) = f2bf(v.x) | (f2bf(v.y) << 16);
    float s = v.x + v.y;
#pragma unroll
    for (int o = 32; o > 0; o >>= 1) s += __shfl_down(s, o);
    __shared__ float red[4];
    if ((t & 63) == 0) red[t >> 6] = s;
    __syncthreads();
    if (t == 0) S[row] = red[0] + red[1] + red[2] + red[3];
}

// ---------------- Stage 1: y = inp @ W_s^T  (bf16 MFMA GEMM, counted-vmcnt pipeline) ----------------
// Triple-buffered LDS, prefetch distance 2, EXPLICIT buffer rotation (no runtime indexing).
// Per K-step (single fused asm -> no reorderable seam):
//   s_waitcnt vmcnt(3) lgkmcnt(0) ; s_barrier
//     vmcnt(3): my tile-k loads landed (only tile k+1's 3 loads may remain) -> RAW-safe
//     lgkmcnt(0): my ds_reads of tile k-1 are COMPLETE before I pass the barrier -> WAR-safe
//   issue tile k+2 into the buffer tile k-1 occupied
//   ds_read + 8 MFMA on tile k
// Loads are never drained to 0 inside the loop (T4 counted-vmcnt).
// BM=128, BN=64 -> grid 1024 = 4 blocks/CU (LDS 36 KB), 16 waves/CU.
#define BM 128
#define BN 64
#define BK 32

__global__ __launch_bounds__(256) void gemm_spatial(
    const ushort_t* __restrict__ A,    // bf16 [16384, 512]
    const ushort_t* __restrict__ Bm,   // bf16 [512, 512]
    ushort_t* __restrict__ Y)          // bf16 [16384, 512]
{
    // 3 buffers x (A 128x32 + B 64x32) bf16 = 3 x 12288 B = 36864 B
    __shared__ __align__(16) ushort_t lds[3 * (BM * BK + BN * BK)];

    const int tid  = threadIdx.x;
    const int wave = tid >> 6;
    const int lane = tid & 63;

    // bijective chunked XCD swizzle (1024 blocks): XCD k gets idx [128k, 128k+128)
    const int bid = blockIdx.x;
    const int idx = (bid & 7) * 128 + (bid >> 3);
    const int n0 = (idx & 7) * BN;     // n fastest: 8 n-blocks of one m-panel adjacent in-XCD
    const int m0 = (idx >> 3) * BM;
    const int wm = (wave >> 1) * 64;   // waves 2x2: each owns 64 m x 32 n
    const int wn = (wave & 1) * 32;

    ushort_t* const As0 = lds;
    ushort_t* const Bs0 = lds + BM * BK;
    ushort_t* const As1 = lds + 6144;
    ushort_t* const Bs1 = lds + 6144 + BM * BK;
    ushort_t* const As2 = lds + 12288;
    ushort_t* const Bs2 = lds + 12288 + BM * BK;

    // staging source addresses (A: 2 instr, B: 1 instr per tile per thread)
    const ushort_t* ga0 = A  + (size_t)(m0 + (tid >> 2)) * ND + (tid & 3) * 8;
    const ushort_t* ga1 = ga0 + (size_t)64 * ND;
    const ushort_t* gb0 = Bm + (size_t)(n0 + (tid >> 2)) * ND + (tid & 3) * 8;

#define ISSUE_TILE(Asb, Bsb, k0) do { \
    __builtin_amdgcn_global_load_lds( \
        (const __attribute__((address_space(1))) unsigned int*)(ga0 + (k0)), \
        (__attribute__((address_space(3))) unsigned int*)((Asb) + tid * 8), 16, 0, 0); \
    __builtin_amdgcn_global_load_lds( \
        (const __attribute__((address_space(1))) unsigned int*)(ga1 + (k0)), \
        (__attribute__((address_space(3))) unsigned int*)((Asb) + 2048 + tid * 8), 16, 0, 0); \
    __builtin_amdgcn_global_load_lds( \
        (const __attribute__((address_space(1))) unsigned int*)(gb0 + (k0)), \
        (__attribute__((address_space(3))) unsigned int*)((Bsb) + tid * 8), 16, 0, 0); \
} while (0)

#define COMPUTE_TILE(Asb, Bsb) do { \
    const ushort_t* a_base = (Asb) + (wm + (lane & 15)) * BK + (lane >> 4) * 8; \
    const ushort_t* b_base = (Bsb) + (wn + (lane & 15)) * BK + (lane >> 4) * 8; \
    short8 af[4], bq[2]; \
    _Pragma("unroll") \
    for (int t = 0; t < 4; ++t) af[t] = *(const short8*)(a_base + t * 16 * BK); \
    _Pragma("unroll") \
    for (int t = 0; t < 2; ++t) bq[t] = *(const short8*)(b_base + t * 16 * BK); \
    _Pragma("unroll") \
    for (int i = 0; i < 4; ++i) \
    _Pragma("unroll") \
    for (int j = 0; j < 2; ++j) \
        acc[i][j] = __builtin_amdgcn_mfma_f32_16x16x32_bf16(af[i], bq[j], acc[i][j], 0, 0, 0); \
} while (0)

// one pipeline step: fused wait+barrier (no seam), then prefetch k+2, then compute k
#define STEP(c, n, k) do { \
    asm volatile("s_waitcnt vmcnt(3) lgkmcnt(0)\n\ts_barrier" ::: "memory"); \
    __builtin_amdgcn_sched_barrier(0); \
    if ((k) + 2 < 16) ISSUE_TILE(As##n, Bs##n, ((k) + 2) * BK); \
    COMPUTE_TILE(As##c, Bs##c); \
} while (0)

    floatx4 acc[4][2] = {};

    // prologue: tiles 0,1 in flight (6 outstanding VMEM per wave)
    ISSUE_TILE(As0, Bs0, 0);
    ISSUE_TILE(As1, Bs1, BK);

    // 15 steps as 5 uniform triples; tile j lives in buffer j%3, all IDs compile-time.
    for (int t = 0; t < 5; ++t) {
        const int k = t * 3;
        STEP(0, 2, k);
        STEP(1, 0, k + 1);
        STEP(2, 1, k + 2);
    }
    // tail: only tile 15's 3 loads outstanding -> full drain, compute buffer 0 (15%3)
    asm volatile("s_waitcnt vmcnt(0) lgkmcnt(0)\n\ts_barrier" ::: "memory");
    __builtin_amdgcn_sched_barrier(0);
    COMPUTE_TILE(As0, Bs0);

#undef STEP
#undef ISSUE_TILE
#undef COMPUTE_TILE

#pragma unroll
    for (int i = 0; i < 4; ++i) {
        const int m_base = m0 + wm + i * 16 + (lane >> 4) * 4;
#pragma unroll
        for (int j = 0; j < 2; ++j) {
            const int n = n0 + wn + j * 16 + (lane & 15);
#pragma unroll
            for (int r = 0; r < 4; ++r) {
                Y[(size_t)(m_base + r) * ND + n] = (ushort_t)f2bf(acc[i][j][r]);
            }
        }
    }
}

// ---------------- Stage 2: temporal mix + biases (fp32 out, nontemporal float4 stores) ----------------
// out[b,w,f,e] = sum_p W_t[f,p]*y[b,w+p,e] + b_t[f]*S[e] + b_s[e]
// Chunked XCD swizzle: XCD k <- batches [8k, 8k+8), matching the GEMM's Y placement.
#define WTILE 8
#define TGRID (((NW + WTILE - 1) / WTILE) * NB)   // 31 * 64 = 1984, % 8 == 0

__global__ __launch_bounds__(256) void temporal_kernel(
    const ushort_t* __restrict__ Y,    // [64*256, 512] bf16
    const float*    __restrict__ Wt,   // [12,12] fp32 (wave-uniform -> s_load)
    const float*    __restrict__ bt,   // [12] fp32
    const float*    __restrict__ bs,   // [512] fp32
    const float*    __restrict__ S,    // [512] fp32
    float*          __restrict__ Out)  // [64,244,12,512] fp32
{
    const int tid = threadIdx.x;
    const int bid = blockIdx.x;
    const int idx = (bid & 7) * (TGRID / 8) + (bid >> 3);   // bijective (1984 % 8 == 0)
    const int b   = idx / 31;          // XCD k gets b in [8k, 8k+8)
    const int wx  = idx % 31;
    const int w0 = wx * WTILE + (tid >> 7) * 4;  // half-block w-base
    const int eq = (tid & 127) * 4;

    const float4 Sv  = *(const float4*)(S + eq);
    const float4 bsv = *(const float4*)(bs + eq);

    // 15-row sliding window, 4 e's per thread, registers only (all indices constant)
    float win[PAST + 3][4];
    const ushort_t* ybase = Y + ((size_t)(b * NL + w0)) * ND + eq;
#pragma unroll
    for (int i = 0; i < PAST + 3; ++i) {
        if (w0 + i < NL) {
            const uint2 v = *(const uint2*)(ybase + (size_t)i * ND);
            win[i][0] = __uint_as_float(v.x << 16);
            win[i][1] = __uint_as_float(v.x & 0xffff0000u);
            win[i][2] = __uint_as_float(v.y << 16);
            win[i][3] = __uint_as_float(v.y & 0xffff0000u);
        } else {
            win[i][0] = win[i][1] = win[i][2] = win[i][3] = 0.f;
        }
    }

#pragma unroll
    for (int w = 0; w < 4; ++w) {
        if (w0 + w < NW) {
            float* orow = Out + ((size_t)(b * NW + (w0 + w)) * FUTURE) * ND + eq;
#pragma unroll
            for (int f = 0; f < FUTURE; ++f) {
                const float btf = bt[f];                    // uniform -> SGPR
                float a0 = fmaf(btf, Sv.x, bsv.x);
                float a1 = fmaf(btf, Sv.y, bsv.y);
                float a2 = fmaf(btf, Sv.z, bsv.z);
                float a3 = fmaf(btf, Sv.w, bsv.w);
#pragma unroll
                for (int p = 0; p < PAST; ++p) {
                    const float c = Wt[f * PAST + p];       // uniform -> SGPR
                    a0 = fmaf(c, win[w + p][0], a0);
                    a1 = fmaf(c, win[w + p][1], a1);
                    a2 = fmaf(c, win[w + p][2], a2);
                    a3 = fmaf(c, win[w + p][3], a3);
                }
                // streaming output, never re-read: bypass L2/L3 (ext_vector type required)
                floatx4 ov;
                ov.x = a0; ov.y = a1; ov.z = a2; ov.w = a3;
                __builtin_nontemporal_store(ov, (floatx4*)(orow + (size_t)f * ND));
            }
        }
    }
}

// ---------------- launch ----------------
extern "C" void kernel_launch(void* const* d_in, const int* in_sizes, int n_in,
                              void* d_out, int out_size, void* d_ws, size_t ws_size,
                              hipStream_t stream) {
    const float* inp = (const float*)d_in[0];  // [64,256,512] fp32
    const float* Wt  = (const float*)d_in[1];  // [12,12]
    const float* bt  = (const float*)d_in[2];  // [12]
    const float* Ws  = (const float*)d_in[3];  // [512,512]
    const float* bs  = (const float*)d_in[4];  // [512]
    float* out = (float*)d_out;

    const size_t n_inp = (size_t)NB * NL * ND;            // 8,388,608
    ushort_t* Y     = (ushort_t*)d_ws;                               // 16.8 MB
    ushort_t* inp_b = (ushort_t*)((char*)d_ws + n_inp * 2);          // +16.8 MB
    ushort_t* Ws_b  = (ushort_t*)((char*)d_ws + n_inp * 4);          // +0.5 MB
    float*    S     = (float*)((char*)d_ws + n_inp * 4 + (size_t)ND * ND * 2);

    prep_ws<<<dim3(ND), dim3(256), 0, stream>>>(Ws, Ws_b, S);
    convert_inp<<<dim3(n_inp / 8 / 256), dim3(256), 0, stream>>>(inp, inp_b);
    gemm_spatial<<<dim3((NB * NL / BM) * (ND / BN)), dim3(256), 0, stream>>>(inp_b, Ws_b, Y);
    temporal_kernel<<<dim3(TGRID), dim3(256), 0, stream>>>(Y, Wt, bt, bs, S, out);
}